// Round 1
// baseline (75.884 us; speedup 1.0000x reference)
//
#include <hip/hip_runtime.h>
#include <math.h>

#define BB 8
#define TT 512
#define DD 128
#define EE 256
#define NT (BB*TT)   // 4096 tokens

// ---------------- Router: softmax(x@Wg+bg), top-2, normalized weights ---------
// One block per token, 256 threads (one per expert).
__global__ __launch_bounds__(256) void router_kernel(
    const float* __restrict__ x,    // [NT, D]
    const float* __restrict__ Wg,   // [D, E]
    const float* __restrict__ bg,   // [E]
    int2*  __restrict__ idx_out,    // [NT]
    float2* __restrict__ w_out)     // [NT]
{
    const int t = blockIdx.x;
    const int e = threadIdx.x;

    __shared__ float xs[DD];
    __shared__ float red[EE];
    __shared__ int   redi[EE];

    if (e < DD) xs[e] = x[(size_t)t * DD + e];
    __syncthreads();

    float logit = bg[e];
    #pragma unroll 8
    for (int d = 0; d < DD; ++d)
        logit = fmaf(xs[d], Wg[d * EE + e], logit);

    // ---- max + argmax ----
    red[e] = logit; redi[e] = e;
    __syncthreads();
    for (int s = EE >> 1; s > 0; s >>= 1) {
        if (e < s) {
            if (red[e + s] > red[e]) { red[e] = red[e + s]; redi[e] = redi[e + s]; }
        }
        __syncthreads();
    }
    const float M  = red[0];
    const int   i1 = redi[0];
    __syncthreads();

    // ---- softmax denominator ----
    const float ex = expf(logit - M);
    red[e] = ex;
    __syncthreads();
    for (int s = EE >> 1; s > 0; s >>= 1) {
        if (e < s) red[e] += red[e + s];
        __syncthreads();
    }
    const float S = red[0];
    __syncthreads();

    // ---- second max (exclude i1) ----
    red[e] = (e == i1) ? -INFINITY : logit; redi[e] = e;
    __syncthreads();
    for (int s = EE >> 1; s > 0; s >>= 1) {
        if (e < s) {
            if (red[e + s] > red[e]) { red[e] = red[e + s]; redi[e] = redi[e + s]; }
        }
        __syncthreads();
    }

    if (e == 0) {
        const float l2 = red[0];
        const int   i2 = redi[0];
        const float p1 = 1.0f / S;            // exp(M-M)/S
        const float p2 = expf(l2 - M) / S;
        const float denom = p1 + p2 + 1e-6f;
        idx_out[t] = make_int2(i1, i2);
        w_out[t]   = make_float2(p1 / denom, p2 / denom);
    }
}

// ---------------- Expert matvecs + mix + SwiGLU + consensus -------------------
// One block per token, 128 threads (one per output dim).
__global__ __launch_bounds__(128) void moe_kernel(
    const float* __restrict__ x,     // [NT, D]
    const float* __restrict__ ew,    // [E, D, D]
    const float* __restrict__ w1,    // [D, D]
    const float* __restrict__ b1,    // [D]
    const float* __restrict__ w2,    // [D, D]
    const float* __restrict__ b2,    // [D]
    const int2*  __restrict__ idx,   // [NT]
    const float2* __restrict__ w,    // [NT]
    float* __restrict__ out_avg,     // [NT, D]
    float* __restrict__ out_cons)    // [NT]
{
    const int t = blockIdx.x;
    const int o = threadIdx.x;

    __shared__ float xs[DD];
    __shared__ float ms[DD];
    __shared__ float wred[2];

    xs[o] = x[(size_t)t * DD + o];
    __syncthreads();

    const int2   ij = idx[t];
    const float2 ww = w[t];
    const float* Wa = ew + (size_t)ij.x * DD * DD;
    const float* Wb = ew + (size_t)ij.y * DD * DD;

    float ya = 0.0f, yb = 0.0f;
    #pragma unroll 4
    for (int d = 0; d < DD; ++d) {
        const float xv = xs[d];
        ya = fmaf(xv, Wa[d * DD + o], ya);
        yb = fmaf(xv, Wb[d * DD + o], yb);
    }

    const float mixed = ww.x * ya + ww.y * yb;
    ms[o] = mixed;
    __syncthreads();

    float g = b1[o], h = b2[o];
    #pragma unroll 4
    for (int d = 0; d < DD; ++d) {
        const float mv = ms[d];
        g = fmaf(mv, w1[d * DD + o], g);
        h = fmaf(mv, w2[d * DD + o], h);
    }

    const float sig  = 1.0f / (1.0f + expf(-g));
    const float wavg = g * sig * h;
    out_avg[(size_t)t * DD + o] = wavg;

    const float da = ya - wavg;
    const float db = yb - wavg;
    float v = ww.x * da * da + ww.y * db * db;

    // wave (64-lane) shuffle reduce, then combine the 2 waves via LDS
    #pragma unroll
    for (int s = 32; s > 0; s >>= 1) v += __shfl_down(v, s);
    if ((o & 63) == 0) wred[o >> 6] = v;
    __syncthreads();
    if (o == 0) out_cons[t] = expf(-(wred[0] + wred[1]) * (1.0f / DD));
}

extern "C" void kernel_launch(void* const* d_in, const int* in_sizes, int n_in,
                              void* d_out, int out_size, void* d_ws, size_t ws_size,
                              hipStream_t stream) {
    const float* x   = (const float*)d_in[0];
    const float* Wg  = (const float*)d_in[1];
    const float* bg  = (const float*)d_in[2];
    const float* ew  = (const float*)d_in[3];
    const float* w1  = (const float*)d_in[4];
    const float* b1  = (const float*)d_in[5];
    const float* w2  = (const float*)d_in[6];
    const float* b2  = (const float*)d_in[7];

    float* out_avg  = (float*)d_out;              // [NT, D]
    float* out_cons = out_avg + (size_t)NT * DD;  // [NT]

    int2*   idx = (int2*)d_ws;                    // 32 KB
    float2* ww  = (float2*)((char*)d_ws + NT * sizeof(int2));  // 32 KB

    router_kernel<<<NT, EE, 0, stream>>>(x, Wg, bg, idx, ww);
    moe_kernel<<<NT, DD, 0, stream>>>(x, ew, w1, b1, w2, b2, idx, ww, out_avg, out_cons);
}